// Round 3
// baseline (393.825 us; speedup 1.0000x reference)
//
#include <hip/hip_runtime.h>
#include <math.h>

#define DIMS 160
#define TS 16              // xy tile
#define CZ 32              // z outputs per block
#define NCH (DIMS/CZ)      // 5 z-chunks
#define RH 7
#define RL 4
#define KH 15
#define KL 9
#define YHR (TS + 2*RH)    // 30 halo rows (high)
#define YLR (TS + 2*RL)    // 24 halo rows (low)
#define SH 34              // sXh row-dim stride (30+4): C-reads & B-writes <=2-way banks
#define SL 28              // sXl row-dim stride (24+4): <=2-way banks
#define NSTEPS (CZ + 2*RH) // 46 planes per block
#define NITER (NSTEPS/2)   // 23 iterations, 2 planes each, 1 barrier each
#define NUNITS (2*(4*YHR + 4*YLR))  // 432 x-conv units per plane-pair

struct DoGW { float gl[KL]; float gh[KH]; };

// Per iteration (2 z-planes): issue global loads for pair p (x-halo windows,
// registers) -> consume pair p-1 from LDS (y-conv + z accumulator-scatter,
// retire 2 outputs) -> x-conv the loaded regs -> write sX[p&1] -> barrier.
// sX is x-major [plane][x][row] so all LDS patterns are <=2-way bank aliased.
__global__ __launch_bounds__(256, 4)
void dog3d_v3(const float* __restrict__ X, float* __restrict__ out, DoGW w) {
  __shared__ float sXh[2][2][TS * SH];   // [buf][plane][x*SH+row] 8704 B
  __shared__ float sXl[2][2][TS * SL];   // 7168 B -> 15.9 KB total

  const int NT = DIMS / TS;  // 10
  const int bid = blockIdx.x;
  const int xt = bid % NT;
  const int yt = (bid / NT) % NT;
  const int zc = (bid / (NT * NT)) % NCH;
  const int b  = bid / (NT * NT * NCH);
  const int x0 = xt * TS, y0 = yt * TS, z0 = zc * CZ;
  const float* Xb = X + (size_t)b * (DIMS * DIMS * DIMS);
  const int tid = threadIdx.x;
  const bool xfast = (x0 >= 8) && (x0 + 24 <= DIMS);  // high needs x0-8..x0+23

  // ---- unit decode (constant per thread) ----
  // unit u in [0,432): pl = u/216; r = u%216; r<120: high(row r>>2, quad r&3)
  //                    else low(row (r-120)>>2, quad (r-120)&3)
  struct Unit { int pl, row, q, yg; bool high, on; };
  auto decode = [&](int u, Unit& un) {
    un.on = (u < NUNITS);
    if (!un.on) return;
    un.pl = u / 216;
    int r = u % 216;
    un.high = (r < 120);
    int rr = un.high ? r : r - 120;
    un.row = rr >> 2;
    un.q = rr & 3;
    int rad = un.high ? RH : RL;
    un.yg = min(max(y0 + un.row - rad, 0), DIMS - 1);
  };
  Unit u1, u2;
  decode(tid, u1);
  decode(tid + 256, u2);   // threads 0..175 carry a second unit (always plane 1)

  auto loadU = [&](const Unit& un, int p0, float v[20]) {
    if (!un.on) return;
    const int p = p0 + un.pl;
    const int zsrc = min(max(z0 - RH + p, 0), DIMS - 1);
    const float* rowp = Xb + ((size_t)zsrc * DIMS + un.yg) * DIMS;
    if (un.high) {
      const int xb = x0 + 4 * un.q - 8;          // 20 floats, 16B aligned when xfast
      if (xfast) {
        #pragma unroll
        for (int t = 0; t < 5; ++t) *(float4*)&v[4 * t] = *(const float4*)(rowp + xb + 4 * t);
      } else {
        #pragma unroll
        for (int i = 0; i < 20; ++i) v[i] = rowp[min(max(xb + i, 0), DIMS - 1)];
      }
    } else {
      const int xb = x0 + 4 * un.q - 4;          // 12 floats
      if (xfast) {
        #pragma unroll
        for (int t = 0; t < 3; ++t) *(float4*)&v[4 * t] = *(const float4*)(rowp + xb + 4 * t);
      } else {
        #pragma unroll
        for (int i = 0; i < 12; ++i) v[i] = rowp[min(max(xb + i, 0), DIMS - 1)];
      }
    }
  };

  auto xconvU = [&](const Unit& un, const float v[20], int buf) {
    if (!un.on) return;
    if (un.high) {
      #pragma unroll
      for (int c = 0; c < 4; ++c) {
        float a = 0.f;
        #pragma unroll
        for (int k = 0; k < KH; ++k) a = fmaf(w.gh[k], v[c + 1 + k], a);
        sXh[buf][un.pl][(4 * un.q + c) * SH + un.row] = a;
      }
    } else {
      #pragma unroll
      for (int c = 0; c < 4; ++c) {
        float a = 0.f;
        #pragma unroll
        for (int k = 0; k < KL; ++k) a = fmaf(w.gl[k], v[c + k], a);
        sXl[buf][un.pl][(4 * un.q + c) * SL + un.row] = a;
      }
    }
  };

  // ---- phase C state: one output column per thread ----
  const int cy = tid >> 4, cx = tid & 15;
  float accH[KH + 1];   // 16: pair-scatter needs index up to 15
  float accL[KL + 5];   // 14: offset 3 (RH-RL) + pair offset 1 + 9 taps
  #pragma unroll
  for (int i = 0; i < KH + 1; ++i) accH[i] = 0.f;
  #pragma unroll
  for (int i = 0; i < KL + 5; ++i) accL[i] = 0.f;

  auto consume = [&](int buf, int p0) {
    #pragma unroll
    for (int pl = 0; pl < 2; ++pl) {
      float ph = 0.f, plv = 0.f;
      #pragma unroll
      for (int j = 0; j < KH; ++j) ph = fmaf(w.gh[j], sXh[buf][pl][cx * SH + cy + j], ph);
      #pragma unroll
      for (int j = 0; j < KL; ++j) plv = fmaf(w.gl[j], sXl[buf][pl][cx * SL + cy + j], plv);
      #pragma unroll
      for (int i = 0; i < KH; ++i) accH[i + pl] = fmaf(w.gh[KH - 1 - i], ph, accH[i + pl]);
      #pragma unroll
      for (int j = 0; j < KL; ++j) accL[j + 3 + pl] = fmaf(w.gl[KL - 1 - j], plv, accL[j + 3 + pl]);
    }
    const int q0 = p0 - 2 * RH;          // oldest pending output
    if (q0 >= 0) {
      const size_t o0 = (((size_t)(b * DIMS + z0 + q0)) * DIMS + (y0 + cy)) * DIMS + (x0 + cx);
      out[o0] = accL[0] - accH[0];
      out[o0 + (size_t)DIMS * DIMS] = accL[1] - accH[1];
    }
    #pragma unroll
    for (int i = 0; i < KH - 1; ++i) accH[i] = accH[i + 2];
    accH[KH - 1] = 0.f; accH[KH] = 0.f;
    #pragma unroll
    for (int i = 0; i < KL + 3; ++i) accL[i] = accL[i + 2];
    accL[KL + 3] = 0.f; accL[KL + 4] = 0.f;
  };

  // ---- pipelined main loop: 1 barrier per 2 planes ----
  float v1[20], v2[20];
  loadU(u1, 0, v1); loadU(u2, 0, v2);
  xconvU(u1, v1, 0); xconvU(u2, v2, 0);
  __syncthreads();
  for (int it = 1; it < NITER; ++it) {
    loadU(u1, 2 * it, v1); loadU(u2, 2 * it, v2);   // in flight during consume
    consume((it - 1) & 1, 2 * (it - 1));
    xconvU(u1, v1, it & 1); xconvU(u2, v2, it & 1);
    __syncthreads();
  }
  consume((NITER - 1) & 1, 2 * (NITER - 1));
}

extern "C" void kernel_launch(void* const* d_in, const int* in_sizes, int n_in,
                              void* d_out, int out_size, void* d_ws, size_t ws_size,
                              hipStream_t stream) {
  const float* X = (const float*)d_in[0];
  float* out = (float*)d_out;

  DoGW w;
  {
    double s = 0.0;
    for (int i = 0; i < KL; ++i) {
      double t = i - (KL - 1) / 2.0;
      double g = exp(-(t * t) / (2.0 * 1.0 * 1.0));
      w.gl[i] = (float)g; s += g;
    }
    for (int i = 0; i < KL; ++i) w.gl[i] = (float)((double)w.gl[i] / s);
    s = 0.0;
    for (int i = 0; i < KH; ++i) {
      double t = i - (KH - 1) / 2.0;
      double g = exp(-(t * t) / (2.0 * 1.6 * 1.6));
      w.gh[i] = (float)g; s += g;
    }
    for (int i = 0; i < KH; ++i) w.gh[i] = (float)((double)w.gh[i] / s);
  }

  const int nblocks = (DIMS / TS) * (DIMS / TS) * NCH * 2;  // 10*10*5*2 = 1000
  dog3d_v3<<<nblocks, 256, 0, stream>>>(X, out, w);
}

// Round 4
// 274.050 us; speedup vs baseline: 1.4371x; 1.4371x over previous
//
#include <hip/hip_runtime.h>
#include <math.h>

#define DIMS 160
#define PLANE (DIMS*DIMS)            // 25600
#define NB 2
#define RH 7
#define RL 4
#define KH 15
#define KL 9
#define TS 16
#define NT (DIMS/TS)                 // 10
#define YHR (TS+2*RH)                // 30 halo rows (high)
#define YLR (TS+2*RL)                // 24 halo rows (low)
#define SH 34                        // sXh x-major stride: all patterns <=2-way banks
#define SL 28                        // sXl stride: <=2-way banks
#define CZ 32                        // z chunk (pass2 / fused)
#define NCH (DIMS/CZ)                // 5
#define NSTEPS (CZ+2*RH)             // 46

struct DoGW { float gl[KL]; float gh[KH]; };

// ---- x-conv of one z-plane's halo rows, direct global -> regs -> LDS ----
// 216 active units: tid<120: high (row 0..29, quad 0..3); 120<=tid<216: low.
// Writes sXh[x*SH+row], sXl[x*SL+row] (x-major; B-writes & C-reads <=2-way).
__device__ __forceinline__ void xconv_plane(const float* __restrict__ Xb, int zsrc,
                                            int x0, int y0, bool xfast, const DoGW& w,
                                            int tid, float* sXh, float* sXl) {
  const size_t zoff = (size_t)zsrc * PLANE;
  if (tid < 120) {
    const int row = tid >> 2, q = tid & 3;
    const int yg = min(max(y0 + row - RH, 0), DIMS - 1);
    const float* rowp = Xb + zoff + (size_t)yg * DIMS;
    const int xb = x0 + 4 * q - 8;
    float v[20];
    if (xfast) {
      #pragma unroll
      for (int t = 0; t < 5; ++t) *(float4*)&v[4 * t] = *(const float4*)(rowp + xb + 4 * t);
    } else {
      #pragma unroll
      for (int i = 0; i < 20; ++i) v[i] = rowp[min(max(xb + i, 0), DIMS - 1)];
    }
    #pragma unroll
    for (int c = 0; c < 4; ++c) {
      float a = 0.f;
      #pragma unroll
      for (int k = 0; k < KH; ++k) a = fmaf(w.gh[k], v[c + 1 + k], a);
      sXh[(4 * q + c) * SH + row] = a;
    }
  } else if (tid < 216) {
    const int u = tid - 120;
    const int row = u >> 2, q = u & 3;
    const int yg = min(max(y0 + row - RL, 0), DIMS - 1);
    const float* rowp = Xb + zoff + (size_t)yg * DIMS;
    const int xb = x0 + 4 * q - 4;
    float v[12];
    if (xfast) {
      #pragma unroll
      for (int t = 0; t < 3; ++t) *(float4*)&v[4 * t] = *(const float4*)(rowp + xb + 4 * t);
    } else {
      #pragma unroll
      for (int i = 0; i < 12; ++i) v[i] = rowp[min(max(xb + i, 0), DIMS - 1)];
    }
    #pragma unroll
    for (int c = 0; c < 4; ++c) {
      float a = 0.f;
      #pragma unroll
      for (int k = 0; k < KL; ++k) a = fmaf(w.gl[k], v[c + k], a);
      sXl[(4 * q + c) * SL + row] = a;
    }
  }
}

// ================= PASS 1: x+y conv, both sigmas -> ws =================
// One (b,z,tile) per block; ONE barrier per block.
__global__ __launch_bounds__(256, 4)
void dog_pass1(const float* __restrict__ X, float* __restrict__ wsH,
               float* __restrict__ wsL, DoGW w) {
  __shared__ float sXh[TS * SH];
  __shared__ float sXl[TS * SL];
  const int bid = blockIdx.x;
  const int xt = bid % NT;
  const int yt = (bid / NT) % NT;
  const int z  = (bid / (NT * NT)) % DIMS;
  const int b  = bid / (NT * NT * DIMS);
  const int x0 = xt * TS, y0 = yt * TS;
  const float* Xb = X + (size_t)b * DIMS * PLANE;
  const int tid = threadIdx.x;
  const bool xfast = (x0 >= 8) && (x0 + 24 <= DIMS);

  xconv_plane(Xb, z, x0, y0, xfast, w, tid, sXh, sXl);
  __syncthreads();

  const int cy = tid >> 4, cx = tid & 15;
  float ph = 0.f, pl = 0.f;
  #pragma unroll
  for (int j = 0; j < KH; ++j) ph = fmaf(w.gh[j], sXh[cx * SH + cy + j], ph);
  #pragma unroll
  for (int j = 0; j < KL; ++j) pl = fmaf(w.gl[j], sXl[cx * SL + cy + j], pl);
  const size_t o = ((size_t)(b * DIMS + z) * DIMS + (y0 + cy)) * DIMS + (x0 + cx);
  wsH[o] = ph;
  wsL[o] = pl;
}

// ================= PASS 2: z conv + DoG, zero LDS, zero barriers =================
__global__ __launch_bounds__(256, 4)
void dog_pass2(const float* __restrict__ wsH, const float* __restrict__ wsL,
               float* __restrict__ out, DoGW w) {
  const int bid = blockIdx.x;
  const int seg = bid % (PLANE / 256);           // 100
  const int zc  = (bid / (PLANE / 256)) % NCH;
  const int b   = bid / ((PLANE / 256) * NCH);
  const int z0  = zc * CZ;
  const int p   = seg * 256 + threadIdx.x;       // offset within plane
  const size_t base = (size_t)b * DIMS * PLANE + p;

  float accH[KH], accL[KL + 3];
  #pragma unroll
  for (int i = 0; i < KH; ++i) accH[i] = 0.f;
  #pragma unroll
  for (int i = 0; i < KL + 3; ++i) accL[i] = 0.f;

  for (int s = 0; s < NSTEPS; ++s) {
    const int zsrc = min(max(z0 - RH + s, 0), DIMS - 1);
    const float vh = wsH[base + (size_t)zsrc * PLANE];
    const float vl = wsL[base + (size_t)zsrc * PLANE];
    #pragma unroll
    for (int i = 0; i < KH; ++i) accH[i] = fmaf(w.gh[KH - 1 - i], vh, accH[i]);
    #pragma unroll
    for (int i = 3; i < KL + 3; ++i) accL[i] = fmaf(w.gl[KL + 2 - i], vl, accL[i]);
    if (s >= 2 * RH) {
      const int zo = z0 + s - 2 * RH;
      out[base + (size_t)zo * PLANE] = accL[0] - accH[0];
    }
    #pragma unroll
    for (int i = 0; i < KH - 1; ++i) accH[i] = accH[i + 1];
    accH[KH - 1] = 0.f;
    #pragma unroll
    for (int i = 0; i < KL + 2; ++i) accL[i] = accL[i + 1];
    accL[KL + 2] = 0.f;
  }
}

// ================= Fallback: fused z-march (if ws too small) =================
// Per step: x-conv (direct global) -> sX[p&1]; barrier; y-conv + z-scatter.
// One barrier per plane; double-buffered sX; no live arrays across phases.
__global__ __launch_bounds__(256, 4)
void dog_fused(const float* __restrict__ X, float* __restrict__ out, DoGW w) {
  __shared__ float sXh[2][TS * SH];
  __shared__ float sXl[2][TS * SL];
  const int bid = blockIdx.x;
  const int xt = bid % NT;
  const int yt = (bid / NT) % NT;
  const int zc = (bid / (NT * NT)) % NCH;
  const int b  = bid / (NT * NT * NCH);
  const int x0 = xt * TS, y0 = yt * TS, z0 = zc * CZ;
  const float* Xb = X + (size_t)b * DIMS * PLANE;
  const int tid = threadIdx.x;
  const bool xfast = (x0 >= 8) && (x0 + 24 <= DIMS);
  const int cy = tid >> 4, cx = tid & 15;

  float accH[KH], accL[KL + 3];
  #pragma unroll
  for (int i = 0; i < KH; ++i) accH[i] = 0.f;
  #pragma unroll
  for (int i = 0; i < KL + 3; ++i) accL[i] = 0.f;

  for (int s = 0; s < NSTEPS; ++s) {
    const int buf = s & 1;
    const int zsrc = min(max(z0 - RH + s, 0), DIMS - 1);
    xconv_plane(Xb, zsrc, x0, y0, xfast, w, tid, sXh[buf], sXl[buf]);
    __syncthreads();
    float ph = 0.f, pl = 0.f;
    #pragma unroll
    for (int j = 0; j < KH; ++j) ph = fmaf(w.gh[j], sXh[buf][cx * SH + cy + j], ph);
    #pragma unroll
    for (int j = 0; j < KL; ++j) pl = fmaf(w.gl[j], sXl[buf][cx * SL + cy + j], pl);
    #pragma unroll
    for (int i = 0; i < KH; ++i) accH[i] = fmaf(w.gh[KH - 1 - i], ph, accH[i]);
    #pragma unroll
    for (int i = 3; i < KL + 3; ++i) accL[i] = fmaf(w.gl[KL + 2 - i], pl, accL[i]);
    if (s >= 2 * RH) {
      const int zo = z0 + s - 2 * RH;
      out[((size_t)(b * DIMS + zo) * DIMS + (y0 + cy)) * DIMS + (x0 + cx)] = accL[0] - accH[0];
    }
    #pragma unroll
    for (int i = 0; i < KH - 1; ++i) accH[i] = accH[i + 1];
    accH[KH - 1] = 0.f;
    #pragma unroll
    for (int i = 0; i < KL + 2; ++i) accL[i] = accL[i + 1];
    accL[KL + 2] = 0.f;
  }
}

extern "C" void kernel_launch(void* const* d_in, const int* in_sizes, int n_in,
                              void* d_out, int out_size, void* d_ws, size_t ws_size,
                              hipStream_t stream) {
  const float* X = (const float*)d_in[0];
  float* out = (float*)d_out;

  DoGW w;
  {
    double s = 0.0;
    for (int i = 0; i < KL; ++i) {
      double t = i - (KL - 1) / 2.0;
      double g = exp(-(t * t) / (2.0 * 1.0 * 1.0));
      w.gl[i] = (float)g; s += g;
    }
    for (int i = 0; i < KL; ++i) w.gl[i] = (float)((double)w.gl[i] / s);
    s = 0.0;
    for (int i = 0; i < KH; ++i) {
      double t = i - (KH - 1) / 2.0;
      double g = exp(-(t * t) / (2.0 * 1.6 * 1.6));
      w.gh[i] = (float)g; s += g;
    }
    for (int i = 0; i < KH; ++i) w.gh[i] = (float)((double)w.gh[i] / s);
  }

  const size_t vox = (size_t)NB * DIMS * PLANE;          // 16.384 M
  const size_t need = 2 * vox * sizeof(float);           // 131 MB? no: 2 vols = 65.5 MB... (vox already includes NB)
  if (ws_size >= need) {
    float* wsH = (float*)d_ws;
    float* wsL = wsH + vox;
    dog_pass1<<<NB * DIMS * NT * NT, 256, 0, stream>>>(X, wsH, wsL, w);
    dog_pass2<<<NB * NCH * (PLANE / 256), 256, 0, stream>>>(wsH, wsL, out, w);
  } else {
    dog_fused<<<NB * NCH * NT * NT, 256, 0, stream>>>(X, out, w);
  }
}